// Round 10
// baseline (21504.454 us; speedup 1.0000x reference)
//
#include <hip/hip_runtime.h>
#include <math.h>

// Problem constants (match reference)
#define NN 50000
#define SEQ 52
#define FIN 16
#define HD 128
#define NEG_SLOPE 0.2f

typedef short bf16x8 __attribute__((ext_vector_type(8)));   // 8 bf16 (4 VGPRs)
typedef float f32x16 __attribute__((ext_vector_type(16)));  // 32x32 MFMA C/D

__device__ __forceinline__ short f2bf(float x) {
    unsigned u = __float_as_uint(x);
    u += 0x7fffu + ((u >> 16) & 1u);   // round-to-nearest-even
    return (short)(u >> 16);
}
__device__ __forceinline__ float b2f(short s) {
    return __uint_as_float(((unsigned)(unsigned short)s) << 16);
}

// ---------------------------------------------------------------------------
// CSR build kernels (run once per launch; graph is static across timesteps)
// ---------------------------------------------------------------------------
__global__ void deg_init_kernel(int* deg, int n) {
    int i = blockIdx.x * blockDim.x + threadIdx.x;
    if (i < n) deg[i] = 1;  // self-loop
}

__global__ void deg_count_kernel(const int* __restrict__ dst, int* deg, int e) {
    int i = blockIdx.x * blockDim.x + threadIdx.x;
    if (i < e) atomicAdd(&deg[dst[i]], 1);
}

__global__ __launch_bounds__(1024) void scan_kernel(const int* __restrict__ deg,
                                                    int* row_ptr, int n) {
    __shared__ int buf[1024];
    __shared__ int carry;
    int tid = threadIdx.x;
    if (tid == 0) carry = 0;
    __syncthreads();
    for (int base = 0; base < n; base += 1024) {
        int i = base + tid;
        int v = (i < n) ? deg[i] : 0;
        buf[tid] = v;
        __syncthreads();
        for (int off = 1; off < 1024; off <<= 1) {
            int t = (tid >= off) ? buf[tid - off] : 0;
            __syncthreads();
            buf[tid] += t;
            __syncthreads();
        }
        if (i < n) row_ptr[i] = carry + buf[tid] - v;  // exclusive
        __syncthreads();
        if (tid == 1023) carry += buf[1023];
        __syncthreads();
    }
    if (tid == 0) row_ptr[n] = carry;
}

__global__ void selfloop_kernel(const int* __restrict__ row_ptr, int* cursor,
                                int* col, int n) {
    int i = blockIdx.x * blockDim.x + threadIdx.x;
    if (i < n) {
        int p = row_ptr[i];
        col[p] = i;          // self-loop first
        cursor[i] = p + 1;
    }
}

__global__ void scatter_kernel(const int* __restrict__ src, const int* __restrict__ dst,
                               int* cursor, int* col, int e) {
    int i = blockIdx.x * blockDim.x + threadIdx.x;
    if (i < e) {
        int p = atomicAdd(&cursor[dst[i]], 1);
        col[p] = src[i];
    }
}

// ---------------------------------------------------------------------------
// Pack W_ih/W_hh into MFMA B-fragment order, split bf16 hi/lo.
// Index: ((((g*4+slab)*8+ks)*4+which)*64+lane)*8 shorts,
//   which: 0=ih_hi 1=ih_lo 2=hh_hi 3=hh_lo
//   col = slab*32 + (lane&31), kcol = ks*16 + (lane>>5)*8
// ---------------------------------------------------------------------------
__global__ void wpack_kernel(const float* __restrict__ Wi, const float* __restrict__ Wh,
                             short* __restrict__ wfrag) {
    int idx = blockIdx.x * blockDim.x + threadIdx.x;
    if (idx >= 3 * 4 * 8 * 4 * 64) return;
    int lane = idx & 63;
    int which = (idx >> 6) & 3;
    int ks = (idx >> 8) & 7;
    int slab = (idx >> 11) & 3;
    int g = idx >> 13;
    int col = slab * 32 + (lane & 31);
    int kcol = ks * 16 + (lane >> 5) * 8;
    const float* Wsrc = (which < 2) ? Wi : Wh;
    const float* row = Wsrc + (size_t)(g * HD + col) * HD + kcol;
    short* dstp = wfrag + (size_t)idx * 8;
    bool lo = (which & 1);
#pragma unroll
    for (int e = 0; e < 8; ++e) {
        float v = row[e];
        short hi = f2bf(v);
        dstp[e] = lo ? f2bf(v - b2f(hi)) : hi;
    }
}

// ---------------------------------------------------------------------------
// Per-timestep kernels
// ---------------------------------------------------------------------------

// xp = x_t @ Wg (stored bf16); a_s = xp.att_src ; a_d = xp.att_dst
// Used ONCE as prologue for t=0; steps 1..51 are produced by gatgru's tail.
__global__ __launch_bounds__(256) void xp_kernel(
    const float* __restrict__ x, const float* __restrict__ Wg,
    const float* __restrict__ att_src, const float* __restrict__ att_dst,
    unsigned* __restrict__ xpb, float* __restrict__ a_s, float* __restrict__ a_d, int n) {
    int wave = (blockIdx.x * blockDim.x + threadIdx.x) >> 6;
    int lane = threadIdx.x & 63;
    if (wave >= n) return;
    const float* xr = x + (size_t)wave * FIN;
    float xv[FIN];
#pragma unroll
    for (int k = 0; k < FIN; ++k) xv[k] = xr[k];
    int c0 = 2 * lane, c1 = 2 * lane + 1;
    float v0 = 0.f, v1 = 0.f;
#pragma unroll
    for (int k = 0; k < FIN; ++k) {
        v0 += xv[k] * Wg[k * HD + c0];
        v1 += xv[k] * Wg[k * HD + c1];
    }
    unsigned p = (unsigned)(unsigned short)f2bf(v0) |
                 ((unsigned)(unsigned short)f2bf(v1) << 16);
    xpb[(size_t)wave * 64 + lane] = p;
    float s = v0 * att_src[c0] + v1 * att_src[c1];
    float d = v0 * att_dst[c0] + v1 * att_dst[c1];
#pragma unroll
    for (int off = 32; off; off >>= 1) {
        s += __shfl_xor(s, off);
        d += __shfl_xor(d, off);
    }
    if (lane == 0) { a_s[wave] = s; a_d[wave] = d; }
}

// ---------------------------------------------------------------------------
// Fused GAT + GRU (+ next-step xp tail) kernel (R10 = R7 + persistent tiles).
// Grid = 1024 blocks (4/CU x 256 CU); each block strides tiles
// bid, bid+1024 (<=2). Removes the 1563-block round-2 tail quantization
// (~25% machine idle in round 2; R7 avg occupancy 32% vs 50% achievable).
// The second tile's GAT gathers issue right after the first tile's GRU in
// the same resident block -- no drain/refill between rounds.
// One extra __syncthreads() per tile protects LDS reuse (epilogue of tile k
// reads sHH/sHL; tile k+1's GAT writes sSH/sSL). Trip count is
// block-uniform -> barrier-safe.
//
// Per-tile body = R7-proven: GAT 16-lane-group/node 4-deep streaming;
// h loads issued early; GRU 2-pass K-loop (combined regs <=128, 4 blk/CU);
// xp tail computes next step's xp for the tile's 32 nodes.
// ---------------------------------------------------------------------------
__global__ __launch_bounds__(256, 4) void gatgru_kernel(
    const int* __restrict__ row_ptr, const int* __restrict__ col,
    const float* __restrict__ a_s, const float* __restrict__ a_d,
    const short* __restrict__ xpb, const float* __restrict__ bias_g,
    float* __restrict__ h, const short* __restrict__ wfrag,
    const float* __restrict__ b_ih, const float* __restrict__ b_hh, int n,
    int ntiles,
    const float* __restrict__ x_next, const float* __restrict__ Wg,
    const float* __restrict__ att_src, const float* __restrict__ att_dst,
    unsigned* __restrict__ xpb_next, float* __restrict__ a_s_next,
    float* __restrict__ a_d_next) {
    __shared__ bf16x8 sSH[512];  // spatial hi (gat output, A-frag layout)
    __shared__ bf16x8 sSL[512];  // spatial lo
    __shared__ bf16x8 sHH[512];  // h hi
    __shared__ bf16x8 sHL[512];  // h lo

    int t = threadIdx.x;
    int lane = t & 63;
    int w = t >> 6;

    for (int tile = blockIdx.x; tile < ntiles; tile += gridDim.x) {
        int n0 = tile * 32;

        // ---- issue h loads early (consumed after gat phase; no LDS) ----
        float h8[2][8];
#pragma unroll
        for (int q = 0; q < 2; ++q) {
            int ks = w * 2 + q;
            int row = n0 + (lane & 31);
            if (row >= n) row = n - 1;
            int kcol = ks * 16 + (lane >> 5) * 8;
            const float* hp = h + (size_t)row * HD + kcol;
            *(float4*)(h8[q]) = *(const float4*)(hp);
            *(float4*)(h8[q] + 4) = *(const float4*)(hp + 4);
        }

        // LDS reuse fence (prev tile's epilogue reads must complete).
        // Harmless on the first iteration; block-uniform trip count.
        __syncthreads();

        // ---- GAT phase: 16-lane group per node, 2 nodes per group ----
        int g = t >> 4;          // group 0..15
        int fg = t & 15;         // feature lane: features fg*8..fg*8+7
        int glane = lane & 0x30; // group base lane within wave

#pragma unroll
        for (int nn = 0; nn < 2; ++nn) {
            int nl = g + nn * 16;   // local node 0..31
            int nd = n0 + nl;
            int sidx = (fg >> 1) * 64 + (fg & 1) * 32 + nl;  // A-frag LDS slot
            if (nd < n) {
                int start = row_ptr[nd], end = row_ptr[nd + 1];
                float ad = a_d[nd];
                float acc[8] = {0.f, 0.f, 0.f, 0.f, 0.f, 0.f, 0.f, 0.f};
                float dpart = 0.f;
                for (int base = start; base < end; base += 16) {
                    int cnt = end - base;
                    if (cnt > 16) cnt = 16;
                    // phase 1: lane fg gathers edge base+fg
                    int s = 0;
                    float wgt = 0.f;
                    if (fg < cnt) {
                        s = col[base + fg];
                        float e = a_s[s] + ad;
                        e = (e > 0.f) ? e : NEG_SLOPE * e;
                        wgt = __expf(e);
                    }
                    dpart += wgt;
                    // phase 2: stream rows, 4 in flight, group-internal shfl
                    for (int k = 0; k < cnt; k += 4) {
                        int si[4];
                        float wt[4];
#pragma unroll
                        for (int u = 0; u < 4; ++u) {
                            int c = k + u;
                            int cc = (c < cnt) ? c : 0;
                            si[u] = __shfl(s, glane | cc);
                            wt[u] = __shfl(wgt, glane | cc);
                            if (c >= cnt) wt[u] = 0.f;
                        }
                        bf16x8 r[4];
#pragma unroll
                        for (int u = 0; u < 4; ++u)
                            r[u] = *(const bf16x8*)(xpb + (size_t)si[u] * HD + fg * 8);
#pragma unroll
                        for (int u = 0; u < 4; ++u)
#pragma unroll
                            for (int j = 0; j < 8; ++j) acc[j] += wt[u] * b2f(r[u][j]);
                    }
                }
                // denom reduce across the 16-lane group
                dpart += __shfl_xor(dpart, 8);
                dpart += __shfl_xor(dpart, 4);
                dpart += __shfl_xor(dpart, 2);
                dpart += __shfl_xor(dpart, 1);
                float inv = __fdividef(1.f, dpart);
                bf16x8 sh, sl;
#pragma unroll
                for (int j = 0; j < 8; ++j) {
                    float o = acc[j] * inv + bias_g[fg * 8 + j];
                    o = fmaxf(o, 0.f);
                    short hi = f2bf(o);
                    sh[j] = hi;
                    sl[j] = f2bf(o - b2f(hi));
                }
                sSH[sidx] = sh;
                sSL[sidx] = sl;
            } else {
                bf16x8 z;
#pragma unroll
                for (int j = 0; j < 8; ++j) z[j] = 0;
                sSH[sidx] = z;
                sSL[sidx] = z;
            }
        }

        // ---- convert + write h tiles (loads drained long ago) ----
#pragma unroll
        for (int q = 0; q < 2; ++q) {
            int ks = w * 2 + q;
            bf16x8 hh, hl;
#pragma unroll
            for (int j = 0; j < 8; ++j) {
                short b = f2bf(h8[q][j]);
                hh[j] = b;
                hl[j] = f2bf(h8[q][j] - b2f(b));
            }
            int li = ks * 64 + lane;
            sHH[li] = hh;
            sHL[li] = hl;
        }
        __syncthreads();

        // ---- GRU phase: 2-pass K-loop (R7) ----
        int j0 = w * 32;
        int cj = lane & 31;       // column within wave's 32-col slab
        int kh = lane >> 5;       // k-half for frags

        // weight base for this wave: + g*65536 + ks*2048 + which*512
        const short* wb = wfrag + (size_t)w * 16384 + (size_t)lane * 8;

        // ---- pass A: r and z gates (merged ih+hh accumulators) ----
        f32x16 arz0, arz1;
#pragma unroll
        for (int r = 0; r < 16; ++r) { arz0[r] = 0.f; arz1[r] = 0.f; }

#pragma unroll
        for (int ks = 0; ks < 8; ++ks) {
            int li = ks * 64 + lane;
            bf16x8 aSH = sSH[li];
            bf16x8 aSL = sSL[li];
            bf16x8 aHH = sHH[li];
            bf16x8 aHL = sHL[li];
            {
                const short* p = wb + 0 * 65536 + ks * 2048;
                bf16x8 wih = *(const bf16x8*)(p);
                bf16x8 wil = *(const bf16x8*)(p + 512);
                bf16x8 whh = *(const bf16x8*)(p + 1024);
                bf16x8 whl = *(const bf16x8*)(p + 1536);
                arz0 = __builtin_amdgcn_mfma_f32_32x32x16_bf16(aSH, wih, arz0, 0, 0, 0);
                arz0 = __builtin_amdgcn_mfma_f32_32x32x16_bf16(aHH, whh, arz0, 0, 0, 0);
                arz0 = __builtin_amdgcn_mfma_f32_32x32x16_bf16(aSL, wih, arz0, 0, 0, 0);
                arz0 = __builtin_amdgcn_mfma_f32_32x32x16_bf16(aHL, whh, arz0, 0, 0, 0);
                arz0 = __builtin_amdgcn_mfma_f32_32x32x16_bf16(aSH, wil, arz0, 0, 0, 0);
                arz0 = __builtin_amdgcn_mfma_f32_32x32x16_bf16(aHH, whl, arz0, 0, 0, 0);
            }
            {
                const short* p = wb + 1 * 65536 + ks * 2048;
                bf16x8 wih = *(const bf16x8*)(p);
                bf16x8 wil = *(const bf16x8*)(p + 512);
                bf16x8 whh = *(const bf16x8*)(p + 1024);
                bf16x8 whl = *(const bf16x8*)(p + 1536);
                arz1 = __builtin_amdgcn_mfma_f32_32x32x16_bf16(aSH, wih, arz1, 0, 0, 0);
                arz1 = __builtin_amdgcn_mfma_f32_32x32x16_bf16(aHH, whh, arz1, 0, 0, 0);
                arz1 = __builtin_amdgcn_mfma_f32_32x32x16_bf16(aSL, wih, arz1, 0, 0, 0);
                arz1 = __builtin_amdgcn_mfma_f32_32x32x16_bf16(aHL, whh, arz1, 0, 0, 0);
                arz1 = __builtin_amdgcn_mfma_f32_32x32x16_bf16(aSH, wil, arz1, 0, 0, 0);
                arz1 = __builtin_amdgcn_mfma_f32_32x32x16_bf16(aHH, whl, arz1, 0, 0, 0);
            }
        }

        // ---- pass B: n gate (separate ih/hh accumulators; r gates h_n) ----
        f32x16 ain, ahn;
#pragma unroll
        for (int r = 0; r < 16; ++r) { ain[r] = 0.f; ahn[r] = 0.f; }

#pragma unroll
        for (int ks = 0; ks < 8; ++ks) {
            int li = ks * 64 + lane;
            bf16x8 aSH = sSH[li];
            bf16x8 aSL = sSL[li];
            bf16x8 aHH = sHH[li];
            bf16x8 aHL = sHL[li];
            const short* p = wb + 2 * 65536 + ks * 2048;
            bf16x8 wih = *(const bf16x8*)(p);
            bf16x8 wil = *(const bf16x8*)(p + 512);
            bf16x8 whh = *(const bf16x8*)(p + 1024);
            bf16x8 whl = *(const bf16x8*)(p + 1536);
            ain = __builtin_amdgcn_mfma_f32_32x32x16_bf16(aSH, wih, ain, 0, 0, 0);
            ahn = __builtin_amdgcn_mfma_f32_32x32x16_bf16(aHH, whh, ahn, 0, 0, 0);
            ain = __builtin_amdgcn_mfma_f32_32x32x16_bf16(aSL, wih, ain, 0, 0, 0);
            ahn = __builtin_amdgcn_mfma_f32_32x32x16_bf16(aHL, whh, ahn, 0, 0, 0);
            ain = __builtin_amdgcn_mfma_f32_32x32x16_bf16(aSH, wil, ain, 0, 0, 0);
            ahn = __builtin_amdgcn_mfma_f32_32x32x16_bf16(aHH, whl, ahn, 0, 0, 0);
        }

        // ---- wave-local GRU elementwise + h write ----
        int j = j0 + cj;
        float brz0 = b_ih[j] + b_hh[j];
        float brz1 = b_ih[HD + j] + b_hh[HD + j];
        float bin_ = b_ih[2 * HD + j];
        float bhn = b_hh[2 * HD + j];
        const short* hhs = (const short*)sHH;
        const short* hls = (const short*)sHL;
        int ksj = j >> 4, halfj = (j >> 3) & 1, ej = j & 7;

#pragma unroll
        for (int r = 0; r < 16; ++r) {
            int nl = (r & 3) + 8 * (r >> 2) + 4 * kh;  // C/D row mapping (m74/m101)
            int node = n0 + nl;
            if (node < n) {
                float rr = __fdividef(1.f, 1.f + __expf(-(arz0[r] + brz0)));
                float zz = __fdividef(1.f, 1.f + __expf(-(arz1[r] + brz1)));
                float u = ain[r] + bin_ + rr * (ahn[r] + bhn);
                float ex = __expf(2.f * u);
                float nn2 = 1.f - __fdividef(2.f, ex + 1.f);  // tanh(u)
                int li = (ksj * 64 + nl + 32 * halfj) * 8 + ej;
                float hold = b2f(hhs[li]) + b2f(hls[li]);
                h[(size_t)node * HD + j] = (1.f - zz) * nn2 + zz * hold;
            }
        }

        // ---- xp TAIL: next-step xp for this tile's 32 nodes ----
        if (x_next != nullptr) {
            int node = n0 + (t >> 3);   // 8 threads per node
            int sub = t & 7;            // cols sub*16 .. sub*16+15
            if (node < n) {
                const float* xr = x_next + (size_t)node * FIN;
                float xv[FIN];
#pragma unroll
                for (int k = 0; k < FIN; ++k) xv[k] = xr[k];
                float s = 0.f, d = 0.f;
                unsigned pk[8];
#pragma unroll
                for (int c = 0; c < 16; c += 2) {
                    int c0 = sub * 16 + c, c1 = c0 + 1;
                    float v0 = 0.f, v1 = 0.f;
#pragma unroll
                    for (int k = 0; k < FIN; ++k) {
                        v0 += xv[k] * Wg[k * HD + c0];
                        v1 += xv[k] * Wg[k * HD + c1];
                    }
                    s += v0 * att_src[c0] + v1 * att_src[c1];
                    d += v0 * att_dst[c0] + v1 * att_dst[c1];
                    pk[c >> 1] = (unsigned)(unsigned short)f2bf(v0) |
                                 ((unsigned)(unsigned short)f2bf(v1) << 16);
                }
                unsigned* dstw = xpb_next + (size_t)node * 64 + sub * 8;
                *(uint4*)(dstw) = make_uint4(pk[0], pk[1], pk[2], pk[3]);
                *(uint4*)(dstw + 4) = make_uint4(pk[4], pk[5], pk[6], pk[7]);
                // reduce a_s/a_d across the node's 8 threads (same wave)
                s += __shfl_xor(s, 1); s += __shfl_xor(s, 2); s += __shfl_xor(s, 4);
                d += __shfl_xor(d, 1); d += __shfl_xor(d, 2); d += __shfl_xor(d, 4);
                if (sub == 0) { a_s_next[node] = s; a_d_next[node] = d; }
            }
        }
    }
}

// out[n] = h[n] . W_fc + b_fc   (one wave per node)
__global__ __launch_bounds__(256) void fc_kernel(
    const float* __restrict__ h, const float* __restrict__ W_fc,
    const float* __restrict__ b_fc, float* __restrict__ out, int n) {
    int wave = (blockIdx.x * blockDim.x + threadIdx.x) >> 6;
    int lane = threadIdx.x & 63;
    if (wave >= n) return;
    float v = h[(size_t)wave * HD + lane] * W_fc[lane] +
              h[(size_t)wave * HD + lane + 64] * W_fc[lane + 64];
#pragma unroll
    for (int off = 32; off; off >>= 1) v += __shfl_xor(v, off);
    if (lane == 0) out[wave] = v + b_fc[0];
}

// ---------------------------------------------------------------------------
extern "C" void kernel_launch(void* const* d_in, const int* in_sizes, int n_in,
                              void* d_out, int out_size, void* d_ws, size_t ws_size,
                              hipStream_t stream) {
    const float* x_seq   = (const float*)d_in[0];
    const int*   ei      = (const int*)d_in[1];
    const float* Wg      = (const float*)d_in[2];
    const float* att_src = (const float*)d_in[3];
    const float* att_dst = (const float*)d_in[4];
    const float* bias_g  = (const float*)d_in[5];
    const float* W_ih    = (const float*)d_in[6];
    const float* W_hh    = (const float*)d_in[7];
    const float* b_ih    = (const float*)d_in[8];
    const float* b_hh    = (const float*)d_in[9];
    const float* W_fc    = (const float*)d_in[10];
    const float* b_fc    = (const float*)d_in[11];
    float* out = (float*)d_out;

    const int N = NN;
    const int E = in_sizes[1] / 2;
    const int* src = ei;
    const int* dst = ei + E;

    // workspace layout
    char* w = (char*)d_ws;
    size_t off = 0;
    auto alloc = [&](size_t bytes) {
        char* p = w + off;
        off = (off + bytes + 255) & ~(size_t)255;
        return p;
    };
    int*   deg     = (int*)alloc((size_t)N * 4);
    int*   row_ptr = (int*)alloc((size_t)(N + 1) * 4);
    int*   cursor  = (int*)alloc((size_t)N * 4);
    int*   col     = (int*)alloc((size_t)(E + N) * 4);
    float* a_s0    = (float*)alloc((size_t)N * 4);
    float* a_d0    = (float*)alloc((size_t)N * 4);
    float* a_s1    = (float*)alloc((size_t)N * 4);
    float* a_d1    = (float*)alloc((size_t)N * 4);
    unsigned* xpb0 = (unsigned*)alloc((size_t)N * 64 * 4);   // bf16 xp [N][128]
    unsigned* xpb1 = (unsigned*)alloc((size_t)N * 64 * 4);
    float* hbuf    = (float*)alloc((size_t)N * HD * 4);
    short* wfrag   = (short*)alloc((size_t)3 * 4 * 8 * 4 * 64 * 8 * 2);  // 393KB

    unsigned* xpbs[2] = {xpb0, xpb1};
    float* a_ss[2] = {a_s0, a_s1};
    float* a_ds[2] = {a_d0, a_d1};

    // h0 = 0
    hipMemsetAsync(hbuf, 0, (size_t)N * HD * 4, stream);

    // CSR build + weight pack (once per launch)
    deg_init_kernel<<<(N + 255) / 256, 256, 0, stream>>>(deg, N);
    deg_count_kernel<<<(E + 255) / 256, 256, 0, stream>>>(dst, deg, E);
    scan_kernel<<<1, 1024, 0, stream>>>(deg, row_ptr, N);
    selfloop_kernel<<<(N + 255) / 256, 256, 0, stream>>>(row_ptr, cursor, col, N);
    scatter_kernel<<<(E + 255) / 256, 256, 0, stream>>>(src, dst, cursor, col, E);
    wpack_kernel<<<(24576 + 255) / 256, 256, 0, stream>>>(W_ih, W_hh, wfrag);

    int node_wave_blocks = (N * 64 + 255) / 256;  // one wave per node
    int ntiles = (N + 31) / 32;                   // 1563
    int persistent_blocks = 1024;                 // 4/CU x 256 CU

    // prologue: xp for t=0 into buffer 0
    xp_kernel<<<node_wave_blocks, 256, 0, stream>>>(x_seq, Wg, att_src, att_dst,
                                                    xpb0, a_s0, a_d0, N);

    for (int t = 0; t < SEQ; ++t) {
        int cur = t & 1, nxt = cur ^ 1;
        const float* xnext = (t + 1 < SEQ) ? (x_seq + (size_t)(t + 1) * N * FIN)
                                           : nullptr;
        gatgru_kernel<<<persistent_blocks, 256, 0, stream>>>(
            row_ptr, col, a_ss[cur], a_ds[cur], (const short*)xpbs[cur], bias_g,
            hbuf, wfrag, b_ih, b_hh, N, ntiles,
            xnext, Wg, att_src, att_dst, xpbs[nxt], a_ss[nxt], a_ds[nxt]);
    }
    fc_kernel<<<node_wave_blocks, 256, 0, stream>>>(hbuf, W_fc, b_fc, out, N);
}

// Round 11
// 6427.660 us; speedup vs baseline: 3.3456x; 3.3456x over previous
//
#include <hip/hip_runtime.h>
#include <math.h>

// Problem constants (match reference)
#define NN 50000
#define SEQ 52
#define FIN 16
#define HD 128
#define NEG_SLOPE 0.2f
#define NRANGE 4       // src-range buckets for L2-phased gathers (R11)
#define RDIV 12500     // range = src / RDIV -> 12500 rows x 256B = 3.2MB < 4MB L2

typedef short bf16x8 __attribute__((ext_vector_type(8)));   // 8 bf16 (4 VGPRs)
typedef float f32x16 __attribute__((ext_vector_type(16)));  // 32x32 MFMA C/D

__device__ __forceinline__ short f2bf(float x) {
    unsigned u = __float_as_uint(x);
    u += 0x7fffu + ((u >> 16) & 1u);   // round-to-nearest-even
    return (short)(u >> 16);
}
__device__ __forceinline__ float b2f(short s) {
    return __uint_as_float(((unsigned)(unsigned short)s) << 16);
}

// ---------------------------------------------------------------------------
// CSR build kernels (run once per launch; graph is static across timesteps)
// R11: CSR is bucketed by (dst, src-range): 4 sub-rows per node, so the GAT
// phase can iterate ranges OUTER and keep each 3.2MB xpb slice L2-resident.
// ---------------------------------------------------------------------------
__global__ void deg_init_kernel(int* deg4, int n4) {
    int i = blockIdx.x * blockDim.x + threadIdx.x;
    if (i < n4) {
        int node = i >> 2, r = i & 3;
        deg4[i] = (r == node / RDIV) ? 1 : 0;  // self-loop in its own bucket
    }
}

__global__ void deg_count_kernel(const int* __restrict__ src,
                                 const int* __restrict__ dst, int* deg4, int e) {
    int i = blockIdx.x * blockDim.x + threadIdx.x;
    if (i < e) atomicAdd(&deg4[dst[i] * 4 + src[i] / RDIV], 1);
}

__global__ __launch_bounds__(1024) void scan_kernel(const int* __restrict__ deg,
                                                    int* row_ptr, int n) {
    __shared__ int buf[1024];
    __shared__ int carry;
    int tid = threadIdx.x;
    if (tid == 0) carry = 0;
    __syncthreads();
    for (int base = 0; base < n; base += 1024) {
        int i = base + tid;
        int v = (i < n) ? deg[i] : 0;
        buf[tid] = v;
        __syncthreads();
        for (int off = 1; off < 1024; off <<= 1) {
            int t = (tid >= off) ? buf[tid - off] : 0;
            __syncthreads();
            buf[tid] += t;
            __syncthreads();
        }
        if (i < n) row_ptr[i] = carry + buf[tid] - v;  // exclusive
        __syncthreads();
        if (tid == 1023) carry += buf[1023];
        __syncthreads();
    }
    if (tid == 0) row_ptr[n] = carry;
}

// init cursors per (node,range); place self-loop in its bucket
__global__ void selfloop_kernel(const int* __restrict__ row_ptr4, int* cursor4,
                                int* col, int n4) {
    int i = blockIdx.x * blockDim.x + threadIdx.x;
    if (i < n4) {
        int node = i >> 2, r = i & 3;
        int base = row_ptr4[i];
        if (r == node / RDIV) {
            col[base] = node;
            cursor4[i] = base + 1;
        } else {
            cursor4[i] = base;
        }
    }
}

__global__ void scatter_kernel(const int* __restrict__ src, const int* __restrict__ dst,
                               int* cursor4, int* col, int e) {
    int i = blockIdx.x * blockDim.x + threadIdx.x;
    if (i < e) {
        int s = src[i];
        int p = atomicAdd(&cursor4[dst[i] * 4 + s / RDIV], 1);
        col[p] = s;
    }
}

// ---------------------------------------------------------------------------
// Pack W_ih/W_hh into MFMA B-fragment order, split bf16 hi/lo.
// Index: ((((g*4+slab)*8+ks)*4+which)*64+lane)*8 shorts,
//   which: 0=ih_hi 1=ih_lo 2=hh_hi 3=hh_lo
//   col = slab*32 + (lane&31), kcol = ks*16 + (lane>>5)*8
// ---------------------------------------------------------------------------
__global__ void wpack_kernel(const float* __restrict__ Wi, const float* __restrict__ Wh,
                             short* __restrict__ wfrag) {
    int idx = blockIdx.x * blockDim.x + threadIdx.x;
    if (idx >= 3 * 4 * 8 * 4 * 64) return;
    int lane = idx & 63;
    int which = (idx >> 6) & 3;
    int ks = (idx >> 8) & 7;
    int slab = (idx >> 11) & 3;
    int g = idx >> 13;
    int col = slab * 32 + (lane & 31);
    int kcol = ks * 16 + (lane >> 5) * 8;
    const float* Wsrc = (which < 2) ? Wi : Wh;
    const float* row = Wsrc + (size_t)(g * HD + col) * HD + kcol;
    short* dstp = wfrag + (size_t)idx * 8;
    bool lo = (which & 1);
#pragma unroll
    for (int e = 0; e < 8; ++e) {
        float v = row[e];
        short hi = f2bf(v);
        dstp[e] = lo ? f2bf(v - b2f(hi)) : hi;
    }
}

// ---------------------------------------------------------------------------
// Per-timestep kernels
// ---------------------------------------------------------------------------

// xp = x_t @ Wg (stored bf16); a_s = xp.att_src ; a_d = xp.att_dst
// Used ONCE as prologue for t=0; steps 1..51 are produced by gatgru's tail.
__global__ __launch_bounds__(256) void xp_kernel(
    const float* __restrict__ x, const float* __restrict__ Wg,
    const float* __restrict__ att_src, const float* __restrict__ att_dst,
    unsigned* __restrict__ xpb, float* __restrict__ a_s, float* __restrict__ a_d, int n) {
    int wave = (blockIdx.x * blockDim.x + threadIdx.x) >> 6;
    int lane = threadIdx.x & 63;
    if (wave >= n) return;
    const float* xr = x + (size_t)wave * FIN;
    float xv[FIN];
#pragma unroll
    for (int k = 0; k < FIN; ++k) xv[k] = xr[k];
    int c0 = 2 * lane, c1 = 2 * lane + 1;
    float v0 = 0.f, v1 = 0.f;
#pragma unroll
    for (int k = 0; k < FIN; ++k) {
        v0 += xv[k] * Wg[k * HD + c0];
        v1 += xv[k] * Wg[k * HD + c1];
    }
    unsigned p = (unsigned)(unsigned short)f2bf(v0) |
                 ((unsigned)(unsigned short)f2bf(v1) << 16);
    xpb[(size_t)wave * 64 + lane] = p;
    float s = v0 * att_src[c0] + v1 * att_src[c1];
    float d = v0 * att_dst[c0] + v1 * att_dst[c1];
#pragma unroll
    for (int off = 32; off; off >>= 1) {
        s += __shfl_xor(s, off);
        d += __shfl_xor(d, off);
    }
    if (lane == 0) { a_s[wave] = s; a_d[wave] = d; }
}

// ---------------------------------------------------------------------------
// Fused GAT + GRU (+ next-step xp tail) kernel (R11 = R7 + src-range phasing).
// Block = 256 threads = 4 waves, owns 32 dst nodes. Grid = 1563 (R10's
// persistent loop REVERTED: it spilled to scratch, WRITE 63->514MB).
//
// Theory (R6->R7: 2x occupancy -> +4% only): the xpb random-row gather
// stream (218MB/dispatch, 12.8MB working set, ~30% L2 hit) saturates the
// L2-miss/L3 service path at ~1.9TB/s. Fix locality, not latency:
// R11 iterates src-ranges OUTER (CSR pre-bucketed by src/12500 into 4
// sub-rows per node). During range-phase p, all blocks gather only from a
// 3.2MB xpb slice -> L2-resident on every XCD -> most gathers become L2
// hits (34.5TB/s aggregate).
// Accumulation across ranges is a plain sum (order-independent up to fp32
// rounding; absmax is bf16-floor dominated).
// GAT per-bucket body, h staging, 2-pass GRU, xp tail: R7-proven,
// unchanged.
// ---------------------------------------------------------------------------
__global__ __launch_bounds__(256, 4) void gatgru_kernel(
    const int* __restrict__ rp4, const int* __restrict__ col,
    const float* __restrict__ a_s, const float* __restrict__ a_d,
    const short* __restrict__ xpb, const float* __restrict__ bias_g,
    float* __restrict__ h, const short* __restrict__ wfrag,
    const float* __restrict__ b_ih, const float* __restrict__ b_hh, int n,
    const float* __restrict__ x_next, const float* __restrict__ Wg,
    const float* __restrict__ att_src, const float* __restrict__ att_dst,
    unsigned* __restrict__ xpb_next, float* __restrict__ a_s_next,
    float* __restrict__ a_d_next) {
    __shared__ bf16x8 sSH[512];  // spatial hi (gat output, A-frag layout)
    __shared__ bf16x8 sSL[512];  // spatial lo
    __shared__ bf16x8 sHH[512];  // h hi
    __shared__ bf16x8 sHL[512];  // h lo

    int t = threadIdx.x;
    int lane = t & 63;
    int w = t >> 6;
    int n0 = blockIdx.x * 32;

    // ---- issue h loads early (consumed after gat phase) ----
    float h8[2][8];
#pragma unroll
    for (int q = 0; q < 2; ++q) {
        int ks = w * 2 + q;
        int row = n0 + (lane & 31);
        if (row >= n) row = n - 1;
        int kcol = ks * 16 + (lane >> 5) * 8;
        const float* hp = h + (size_t)row * HD + kcol;
        *(float4*)(h8[q]) = *(const float4*)(hp);
        *(float4*)(h8[q] + 4) = *(const float4*)(hp + 4);
    }

    // ---- GAT phase: 16-lane group per node, 2 nodes per group,
    //      src-range OUTER loop for L2-phased gathers ----
    int g = t >> 4;          // group 0..15
    int fg = t & 15;         // feature lane: features fg*8..fg*8+7
    int glane = lane & 0x30; // group base lane within wave

    float acc[2][8];
    float dpart[2] = {0.f, 0.f};
    float adv[2];
#pragma unroll
    for (int nn = 0; nn < 2; ++nn) {
#pragma unroll
        for (int j = 0; j < 8; ++j) acc[nn][j] = 0.f;
        int nd = n0 + g + nn * 16;
        adv[nn] = (nd < n) ? a_d[nd] : 0.f;
    }

#pragma unroll
    for (int p = 0; p < NRANGE; ++p) {
#pragma unroll
        for (int nn = 0; nn < 2; ++nn) {
            int nd = n0 + g + nn * 16;
            if (nd < n) {
                int start = rp4[nd * 4 + p], end = rp4[nd * 4 + p + 1];
                for (int base = start; base < end; base += 16) {
                    int cnt = end - base;
                    if (cnt > 16) cnt = 16;
                    // phase 1: lane fg gathers edge base+fg of this bucket
                    int s = 0;
                    float wgt = 0.f;
                    if (fg < cnt) {
                        s = col[base + fg];
                        float e = a_s[s] + adv[nn];
                        e = (e > 0.f) ? e : NEG_SLOPE * e;
                        wgt = __expf(e);
                    }
                    dpart[nn] += wgt;
                    // phase 2: stream rows, 4 in flight, group-internal shfl
                    for (int k = 0; k < cnt; k += 4) {
                        int si[4];
                        float wt[4];
#pragma unroll
                        for (int u = 0; u < 4; ++u) {
                            int c = k + u;
                            int cc = (c < cnt) ? c : 0;
                            si[u] = __shfl(s, glane | cc);
                            wt[u] = __shfl(wgt, glane | cc);
                            if (c >= cnt) wt[u] = 0.f;
                        }
                        bf16x8 r[4];
#pragma unroll
                        for (int u = 0; u < 4; ++u)
                            r[u] = *(const bf16x8*)(xpb + (size_t)si[u] * HD + fg * 8);
#pragma unroll
                        for (int u = 0; u < 4; ++u)
#pragma unroll
                            for (int j = 0; j < 8; ++j)
                                acc[nn][j] += wt[u] * b2f(r[u][j]);
                    }
                }
            }
        }
    }

    // ---- GAT epilogue: normalize, bias, relu, split-bf16 -> LDS ----
#pragma unroll
    for (int nn = 0; nn < 2; ++nn) {
        int nl = g + nn * 16;
        int nd = n0 + nl;
        int sidx = (fg >> 1) * 64 + (fg & 1) * 32 + nl;  // A-frag LDS slot
        if (nd < n) {
            float dp = dpart[nn];
            dp += __shfl_xor(dp, 8);
            dp += __shfl_xor(dp, 4);
            dp += __shfl_xor(dp, 2);
            dp += __shfl_xor(dp, 1);
            float inv = __fdividef(1.f, dp);
            bf16x8 sh, sl;
#pragma unroll
            for (int j = 0; j < 8; ++j) {
                float o = acc[nn][j] * inv + bias_g[fg * 8 + j];
                o = fmaxf(o, 0.f);
                short hi = f2bf(o);
                sh[j] = hi;
                sl[j] = f2bf(o - b2f(hi));
            }
            sSH[sidx] = sh;
            sSL[sidx] = sl;
        } else {
            bf16x8 z;
#pragma unroll
            for (int j = 0; j < 8; ++j) z[j] = 0;
            sSH[sidx] = z;
            sSL[sidx] = z;
        }
    }

    // ---- convert + write h tiles (loads drained long ago) ----
#pragma unroll
    for (int q = 0; q < 2; ++q) {
        int ks = w * 2 + q;
        bf16x8 hh, hl;
#pragma unroll
        for (int j = 0; j < 8; ++j) {
            short b = f2bf(h8[q][j]);
            hh[j] = b;
            hl[j] = f2bf(h8[q][j] - b2f(b));
        }
        int li = ks * 64 + lane;
        sHH[li] = hh;
        sHL[li] = hl;
    }
    __syncthreads();

    // ---- GRU phase: 2-pass K-loop (R7) ----
    int j0 = w * 32;
    int cj = lane & 31;       // column within wave's 32-col slab
    int kh = lane >> 5;       // k-half for frags

    // fragment-ordered weight base for this wave: + g*65536 + ks*2048 + which*512
    const short* wb = wfrag + (size_t)w * 16384 + (size_t)lane * 8;

    // ---- pass A: r and z gates (merged ih+hh accumulators) ----
    f32x16 arz0, arz1;
#pragma unroll
    for (int r = 0; r < 16; ++r) { arz0[r] = 0.f; arz1[r] = 0.f; }

#pragma unroll
    for (int ks = 0; ks < 8; ++ks) {
        int li = ks * 64 + lane;
        bf16x8 aSH = sSH[li];
        bf16x8 aSL = sSL[li];
        bf16x8 aHH = sHH[li];
        bf16x8 aHL = sHL[li];
        {
            const short* p = wb + 0 * 65536 + ks * 2048;
            bf16x8 wih = *(const bf16x8*)(p);
            bf16x8 wil = *(const bf16x8*)(p + 512);
            bf16x8 whh = *(const bf16x8*)(p + 1024);
            bf16x8 whl = *(const bf16x8*)(p + 1536);
            arz0 = __builtin_amdgcn_mfma_f32_32x32x16_bf16(aSH, wih, arz0, 0, 0, 0);
            arz0 = __builtin_amdgcn_mfma_f32_32x32x16_bf16(aHH, whh, arz0, 0, 0, 0);
            arz0 = __builtin_amdgcn_mfma_f32_32x32x16_bf16(aSL, wih, arz0, 0, 0, 0);
            arz0 = __builtin_amdgcn_mfma_f32_32x32x16_bf16(aHL, whh, arz0, 0, 0, 0);
            arz0 = __builtin_amdgcn_mfma_f32_32x32x16_bf16(aSH, wil, arz0, 0, 0, 0);
            arz0 = __builtin_amdgcn_mfma_f32_32x32x16_bf16(aHH, whl, arz0, 0, 0, 0);
        }
        {
            const short* p = wb + 1 * 65536 + ks * 2048;
            bf16x8 wih = *(const bf16x8*)(p);
            bf16x8 wil = *(const bf16x8*)(p + 512);
            bf16x8 whh = *(const bf16x8*)(p + 1024);
            bf16x8 whl = *(const bf16x8*)(p + 1536);
            arz1 = __builtin_amdgcn_mfma_f32_32x32x16_bf16(aSH, wih, arz1, 0, 0, 0);
            arz1 = __builtin_amdgcn_mfma_f32_32x32x16_bf16(aHH, whh, arz1, 0, 0, 0);
            arz1 = __builtin_amdgcn_mfma_f32_32x32x16_bf16(aSL, wih, arz1, 0, 0, 0);
            arz1 = __builtin_amdgcn_mfma_f32_32x32x16_bf16(aHL, whh, arz1, 0, 0, 0);
            arz1 = __builtin_amdgcn_mfma_f32_32x32x16_bf16(aSH, wil, arz1, 0, 0, 0);
            arz1 = __builtin_amdgcn_mfma_f32_32x32x16_bf16(aHH, whl, arz1, 0, 0, 0);
        }
    }

    // ---- pass B: n gate (separate ih/hh accumulators; r gates h_n) ----
    f32x16 ain, ahn;
#pragma unroll
    for (int r = 0; r < 16; ++r) { ain[r] = 0.f; ahn[r] = 0.f; }

#pragma unroll
    for (int ks = 0; ks < 8; ++ks) {
        int li = ks * 64 + lane;
        bf16x8 aSH = sSH[li];
        bf16x8 aSL = sSL[li];
        bf16x8 aHH = sHH[li];
        bf16x8 aHL = sHL[li];
        const short* p = wb + 2 * 65536 + ks * 2048;
        bf16x8 wih = *(const bf16x8*)(p);
        bf16x8 wil = *(const bf16x8*)(p + 512);
        bf16x8 whh = *(const bf16x8*)(p + 1024);
        bf16x8 whl = *(const bf16x8*)(p + 1536);
        ain = __builtin_amdgcn_mfma_f32_32x32x16_bf16(aSH, wih, ain, 0, 0, 0);
        ahn = __builtin_amdgcn_mfma_f32_32x32x16_bf16(aHH, whh, ahn, 0, 0, 0);
        ain = __builtin_amdgcn_mfma_f32_32x32x16_bf16(aSL, wih, ain, 0, 0, 0);
        ahn = __builtin_amdgcn_mfma_f32_32x32x16_bf16(aHL, whh, ahn, 0, 0, 0);
        ain = __builtin_amdgcn_mfma_f32_32x32x16_bf16(aSH, wil, ain, 0, 0, 0);
        ahn = __builtin_amdgcn_mfma_f32_32x32x16_bf16(aHH, whl, ahn, 0, 0, 0);
    }

    // ---- wave-local GRU elementwise + h write ----
    int j = j0 + cj;
    float brz0 = b_ih[j] + b_hh[j];
    float brz1 = b_ih[HD + j] + b_hh[HD + j];
    float bin_ = b_ih[2 * HD + j];
    float bhn = b_hh[2 * HD + j];
    const short* hhs = (const short*)sHH;
    const short* hls = (const short*)sHL;
    int ksj = j >> 4, halfj = (j >> 3) & 1, ej = j & 7;

#pragma unroll
    for (int r = 0; r < 16; ++r) {
        int nl = (r & 3) + 8 * (r >> 2) + 4 * kh;  // C/D row mapping (m74/m101)
        int node = n0 + nl;
        if (node < n) {
            float rr = __fdividef(1.f, 1.f + __expf(-(arz0[r] + brz0)));
            float zz = __fdividef(1.f, 1.f + __expf(-(arz1[r] + brz1)));
            float u = ain[r] + bin_ + rr * (ahn[r] + bhn);
            float ex = __expf(2.f * u);
            float nn2 = 1.f - __fdividef(2.f, ex + 1.f);  // tanh(u)
            int li = (ksj * 64 + nl + 32 * halfj) * 8 + ej;
            float hold = b2f(hhs[li]) + b2f(hls[li]);
            h[(size_t)node * HD + j] = (1.f - zz) * nn2 + zz * hold;
        }
    }

    // ---- xp TAIL: next-step xp for this block's 32 nodes ----
    if (x_next != nullptr) {
        int node = n0 + (t >> 3);   // 8 threads per node
        int sub = t & 7;            // cols sub*16 .. sub*16+15
        if (node < n) {
            const float* xr = x_next + (size_t)node * FIN;
            float xv[FIN];
#pragma unroll
            for (int k = 0; k < FIN; ++k) xv[k] = xr[k];
            float s = 0.f, d = 0.f;
            unsigned pk[8];
#pragma unroll
            for (int c = 0; c < 16; c += 2) {
                int c0 = sub * 16 + c, c1 = c0 + 1;
                float v0 = 0.f, v1 = 0.f;
#pragma unroll
                for (int k = 0; k < FIN; ++k) {
                    v0 += xv[k] * Wg[k * HD + c0];
                    v1 += xv[k] * Wg[k * HD + c1];
                }
                s += v0 * att_src[c0] + v1 * att_src[c1];
                d += v0 * att_dst[c0] + v1 * att_dst[c1];
                pk[c >> 1] = (unsigned)(unsigned short)f2bf(v0) |
                             ((unsigned)(unsigned short)f2bf(v1) << 16);
            }
            unsigned* dstw = xpb_next + (size_t)node * 64 + sub * 8;
            *(uint4*)(dstw) = make_uint4(pk[0], pk[1], pk[2], pk[3]);
            *(uint4*)(dstw + 4) = make_uint4(pk[4], pk[5], pk[6], pk[7]);
            // reduce a_s/a_d across the node's 8 threads (same wave)
            s += __shfl_xor(s, 1); s += __shfl_xor(s, 2); s += __shfl_xor(s, 4);
            d += __shfl_xor(d, 1); d += __shfl_xor(d, 2); d += __shfl_xor(d, 4);
            if (sub == 0) { a_s_next[node] = s; a_d_next[node] = d; }
        }
    }
}

// out[n] = h[n] . W_fc + b_fc   (one wave per node)
__global__ __launch_bounds__(256) void fc_kernel(
    const float* __restrict__ h, const float* __restrict__ W_fc,
    const float* __restrict__ b_fc, float* __restrict__ out, int n) {
    int wave = (blockIdx.x * blockDim.x + threadIdx.x) >> 6;
    int lane = threadIdx.x & 63;
    if (wave >= n) return;
    float v = h[(size_t)wave * HD + lane] * W_fc[lane] +
              h[(size_t)wave * HD + lane + 64] * W_fc[lane + 64];
#pragma unroll
    for (int off = 32; off; off >>= 1) v += __shfl_xor(v, off);
    if (lane == 0) out[wave] = v + b_fc[0];
}

// ---------------------------------------------------------------------------
extern "C" void kernel_launch(void* const* d_in, const int* in_sizes, int n_in,
                              void* d_out, int out_size, void* d_ws, size_t ws_size,
                              hipStream_t stream) {
    const float* x_seq   = (const float*)d_in[0];
    const int*   ei      = (const int*)d_in[1];
    const float* Wg      = (const float*)d_in[2];
    const float* att_src = (const float*)d_in[3];
    const float* att_dst = (const float*)d_in[4];
    const float* bias_g  = (const float*)d_in[5];
    const float* W_ih    = (const float*)d_in[6];
    const float* W_hh    = (const float*)d_in[7];
    const float* b_ih    = (const float*)d_in[8];
    const float* b_hh    = (const float*)d_in[9];
    const float* W_fc    = (const float*)d_in[10];
    const float* b_fc    = (const float*)d_in[11];
    float* out = (float*)d_out;

    const int N = NN;
    const int E = in_sizes[1] / 2;
    const int* src = ei;
    const int* dst = ei + E;

    // workspace layout
    char* w = (char*)d_ws;
    size_t off = 0;
    auto alloc = [&](size_t bytes) {
        char* p = w + off;
        off = (off + bytes + 255) & ~(size_t)255;
        return p;
    };
    int*   deg4    = (int*)alloc((size_t)N * 4 * 4);          // per (node,range)
    int*   rp4     = (int*)alloc(((size_t)N * 4 + 1) * 4);    // bucketed CSR
    int*   cursor4 = (int*)alloc((size_t)N * 4 * 4);
    int*   col     = (int*)alloc((size_t)(E + N) * 4);
    float* a_s0    = (float*)alloc((size_t)N * 4);
    float* a_d0    = (float*)alloc((size_t)N * 4);
    float* a_s1    = (float*)alloc((size_t)N * 4);
    float* a_d1    = (float*)alloc((size_t)N * 4);
    unsigned* xpb0 = (unsigned*)alloc((size_t)N * 64 * 4);    // bf16 xp [N][128]
    unsigned* xpb1 = (unsigned*)alloc((size_t)N * 64 * 4);
    float* hbuf    = (float*)alloc((size_t)N * HD * 4);
    short* wfrag   = (short*)alloc((size_t)3 * 4 * 8 * 4 * 64 * 8 * 2);  // 393KB

    unsigned* xpbs[2] = {xpb0, xpb1};
    float* a_ss[2] = {a_s0, a_s1};
    float* a_ds[2] = {a_d0, a_d1};

    // h0 = 0
    hipMemsetAsync(hbuf, 0, (size_t)N * HD * 4, stream);

    // CSR build (bucketed by src-range) + weight pack (once per launch)
    int n4 = N * 4;
    deg_init_kernel<<<(n4 + 255) / 256, 256, 0, stream>>>(deg4, n4);
    deg_count_kernel<<<(E + 255) / 256, 256, 0, stream>>>(src, dst, deg4, E);
    scan_kernel<<<1, 1024, 0, stream>>>(deg4, rp4, n4);
    selfloop_kernel<<<(n4 + 255) / 256, 256, 0, stream>>>(rp4, cursor4, col, n4);
    scatter_kernel<<<(E + 255) / 256, 256, 0, stream>>>(src, dst, cursor4, col, E);
    wpack_kernel<<<(24576 + 255) / 256, 256, 0, stream>>>(W_ih, W_hh, wfrag);

    int node_wave_blocks = (N * 64 + 255) / 256;  // one wave per node
    int fused_blocks = (N + 31) / 32;             // 32-node fused tiles

    // prologue: xp for t=0 into buffer 0
    xp_kernel<<<node_wave_blocks, 256, 0, stream>>>(x_seq, Wg, att_src, att_dst,
                                                    xpb0, a_s0, a_d0, N);

    for (int t = 0; t < SEQ; ++t) {
        int cur = t & 1, nxt = cur ^ 1;
        const float* xnext = (t + 1 < SEQ) ? (x_seq + (size_t)(t + 1) * N * FIN)
                                           : nullptr;
        gatgru_kernel<<<fused_blocks, 256, 0, stream>>>(
            rp4, col, a_ss[cur], a_ds[cur], (const short*)xpbs[cur], bias_g,
            hbuf, wfrag, b_ih, b_hh, N,
            xnext, Wg, att_src, att_dst, xpbs[nxt], a_ss[nxt], a_ds[nxt]);
    }
    fc_kernel<<<node_wave_blocks, 256, 0, stream>>>(hbuf, W_fc, b_fc, out, N);
}

// Round 12
// 5512.307 us; speedup vs baseline: 3.9012x; 1.1661x over previous
//
#include <hip/hip_runtime.h>
#include <math.h>

// Problem constants (match reference)
#define NN 50000
#define SEQ 52
#define FIN 16
#define HD 128
#define NEG_SLOPE 0.2f

typedef short bf16x8 __attribute__((ext_vector_type(8)));   // 8 bf16 (4 VGPRs)
typedef float f32x16 __attribute__((ext_vector_type(16)));  // 32x32 MFMA C/D

__device__ __forceinline__ short f2bf(float x) {
    unsigned u = __float_as_uint(x);
    u += 0x7fffu + ((u >> 16) & 1u);   // round-to-nearest-even
    return (short)(u >> 16);
}
__device__ __forceinline__ float b2f(short s) {
    return __uint_as_float(((unsigned)(unsigned short)s) << 16);
}

// ---------------------------------------------------------------------------
// CSR build kernels (run once per launch; graph is static across timesteps)
// (R12: bucketed CSR reverted -- scan over 4N cost +270us, phasing neutral)
// ---------------------------------------------------------------------------
__global__ void deg_init_kernel(int* deg, int n) {
    int i = blockIdx.x * blockDim.x + threadIdx.x;
    if (i < n) deg[i] = 1;  // self-loop
}

__global__ void deg_count_kernel(const int* __restrict__ dst, int* deg, int e) {
    int i = blockIdx.x * blockDim.x + threadIdx.x;
    if (i < e) atomicAdd(&deg[dst[i]], 1);
}

__global__ __launch_bounds__(1024) void scan_kernel(const int* __restrict__ deg,
                                                    int* row_ptr, int n) {
    __shared__ int buf[1024];
    __shared__ int carry;
    int tid = threadIdx.x;
    if (tid == 0) carry = 0;
    __syncthreads();
    for (int base = 0; base < n; base += 1024) {
        int i = base + tid;
        int v = (i < n) ? deg[i] : 0;
        buf[tid] = v;
        __syncthreads();
        for (int off = 1; off < 1024; off <<= 1) {
            int t = (tid >= off) ? buf[tid - off] : 0;
            __syncthreads();
            buf[tid] += t;
            __syncthreads();
        }
        if (i < n) row_ptr[i] = carry + buf[tid] - v;  // exclusive
        __syncthreads();
        if (tid == 1023) carry += buf[1023];
        __syncthreads();
    }
    if (tid == 0) row_ptr[n] = carry;
}

__global__ void selfloop_kernel(const int* __restrict__ row_ptr, int* cursor,
                                int* col, int n) {
    int i = blockIdx.x * blockDim.x + threadIdx.x;
    if (i < n) {
        int p = row_ptr[i];
        col[p] = i;          // self-loop first
        cursor[i] = p + 1;
    }
}

__global__ void scatter_kernel(const int* __restrict__ src, const int* __restrict__ dst,
                               int* cursor, int* col, int e) {
    int i = blockIdx.x * blockDim.x + threadIdx.x;
    if (i < e) {
        int p = atomicAdd(&cursor[dst[i]], 1);
        col[p] = src[i];
    }
}

// ---------------------------------------------------------------------------
// Pack W_ih/W_hh into MFMA B-fragment order, split bf16 hi/lo.
// Index: ((((g*4+slab)*8+ks)*4+which)*64+lane)*8 shorts,
//   which: 0=ih_hi 1=ih_lo 2=hh_hi 3=hh_lo
//   col = slab*32 + (lane&31), kcol = ks*16 + (lane>>5)*8
// ---------------------------------------------------------------------------
__global__ void wpack_kernel(const float* __restrict__ Wi, const float* __restrict__ Wh,
                             short* __restrict__ wfrag) {
    int idx = blockIdx.x * blockDim.x + threadIdx.x;
    if (idx >= 3 * 4 * 8 * 4 * 64) return;
    int lane = idx & 63;
    int which = (idx >> 6) & 3;
    int ks = (idx >> 8) & 7;
    int slab = (idx >> 11) & 3;
    int g = idx >> 13;
    int col = slab * 32 + (lane & 31);
    int kcol = ks * 16 + (lane >> 5) * 8;
    const float* Wsrc = (which < 2) ? Wi : Wh;
    const float* row = Wsrc + (size_t)(g * HD + col) * HD + kcol;
    short* dstp = wfrag + (size_t)idx * 8;
    bool lo = (which & 1);
#pragma unroll
    for (int e = 0; e < 8; ++e) {
        float v = row[e];
        short hi = f2bf(v);
        dstp[e] = lo ? f2bf(v - b2f(hi)) : hi;
    }
}

// ---------------------------------------------------------------------------
// Per-timestep kernels
// ---------------------------------------------------------------------------

// xp = x_t @ Wg (stored bf16); a_s = xp.att_src ; a_d = xp.att_dst
// Used ONCE as prologue for t=0; steps 1..51 are produced by gatgru's tail.
__global__ __launch_bounds__(256) void xp_kernel(
    const float* __restrict__ x, const float* __restrict__ Wg,
    const float* __restrict__ att_src, const float* __restrict__ att_dst,
    unsigned* __restrict__ xpb, float* __restrict__ a_s, float* __restrict__ a_d, int n) {
    int wave = (blockIdx.x * blockDim.x + threadIdx.x) >> 6;
    int lane = threadIdx.x & 63;
    if (wave >= n) return;
    const float* xr = x + (size_t)wave * FIN;
    float xv[FIN];
#pragma unroll
    for (int k = 0; k < FIN; ++k) xv[k] = xr[k];
    int c0 = 2 * lane, c1 = 2 * lane + 1;
    float v0 = 0.f, v1 = 0.f;
#pragma unroll
    for (int k = 0; k < FIN; ++k) {
        v0 += xv[k] * Wg[k * HD + c0];
        v1 += xv[k] * Wg[k * HD + c1];
    }
    unsigned p = (unsigned)(unsigned short)f2bf(v0) |
                 ((unsigned)(unsigned short)f2bf(v1) << 16);
    xpb[(size_t)wave * 64 + lane] = p;
    float s = v0 * att_src[c0] + v1 * att_src[c1];
    float d = v0 * att_dst[c0] + v1 * att_dst[c1];
#pragma unroll
    for (int off = 32; off; off >>= 1) {
        s += __shfl_xor(s, off);
        d += __shfl_xor(d, off);
    }
    if (lane == 0) { a_s[wave] = s; a_d[wave] = d; }
}

// ---------------------------------------------------------------------------
// Fused GAT + GRU (+ next-step xp tail) kernel (R12 = R7 + vectorized tail).
// Block = 256 threads = 4 waves, owns 32 dst nodes. Grid = 1563.
//
// Model (fits the 113-120us invariance across R6/R7/R9/R11): time = total
// L1/TA cache-line touches / fixed per-CU line rate. Per-CU per dispatch:
// xp-tail scalar Wg loads ~50k touches (LARGEST, untouched so far), GRU
// weights 37.5k, GAT gathers 13k, misc 8k. R12 attacks the tail term:
// float4 Wg/att reads -> 2048 -> 512 line-touches per wave (-75% of the
// biggest term). GAT phase, h staging, 2-pass GRU: R7-proven, unchanged.
// ---------------------------------------------------------------------------
__global__ __launch_bounds__(256, 4) void gatgru_kernel(
    const int* __restrict__ row_ptr, const int* __restrict__ col,
    const float* __restrict__ a_s, const float* __restrict__ a_d,
    const short* __restrict__ xpb, const float* __restrict__ bias_g,
    float* __restrict__ h, const short* __restrict__ wfrag,
    const float* __restrict__ b_ih, const float* __restrict__ b_hh, int n,
    const float* __restrict__ x_next, const float* __restrict__ Wg,
    const float* __restrict__ att_src, const float* __restrict__ att_dst,
    unsigned* __restrict__ xpb_next, float* __restrict__ a_s_next,
    float* __restrict__ a_d_next) {
    __shared__ bf16x8 sSH[512];  // spatial hi (gat output, A-frag layout)
    __shared__ bf16x8 sSL[512];  // spatial lo
    __shared__ bf16x8 sHH[512];  // h hi
    __shared__ bf16x8 sHL[512];  // h lo

    int t = threadIdx.x;
    int lane = t & 63;
    int w = t >> 6;
    int n0 = blockIdx.x * 32;

    // ---- issue h loads early (consumed after gat phase) ----
    float h8[2][8];
#pragma unroll
    for (int q = 0; q < 2; ++q) {
        int ks = w * 2 + q;
        int row = n0 + (lane & 31);
        if (row >= n) row = n - 1;
        int kcol = ks * 16 + (lane >> 5) * 8;
        const float* hp = h + (size_t)row * HD + kcol;
        *(float4*)(h8[q]) = *(const float4*)(hp);
        *(float4*)(h8[q] + 4) = *(const float4*)(hp + 4);
    }

    // ---- GAT phase: 16-lane group per node, 2 nodes per group ----
    int g = t >> 4;          // group 0..15
    int fg = t & 15;         // feature lane: features fg*8..fg*8+7
    int glane = lane & 0x30; // group base lane within wave

#pragma unroll
    for (int nn = 0; nn < 2; ++nn) {
        int nl = g + nn * 16;   // local node 0..31
        int nd = n0 + nl;
        int sidx = (fg >> 1) * 64 + (fg & 1) * 32 + nl;  // A-frag LDS slot
        if (nd < n) {
            int start = row_ptr[nd], end = row_ptr[nd + 1];
            float ad = a_d[nd];
            float acc[8] = {0.f, 0.f, 0.f, 0.f, 0.f, 0.f, 0.f, 0.f};
            float dpart = 0.f;
            for (int base = start; base < end; base += 16) {
                int cnt = end - base;
                if (cnt > 16) cnt = 16;
                // phase 1: lane fg gathers edge base+fg
                int s = 0;
                float wgt = 0.f;
                if (fg < cnt) {
                    s = col[base + fg];
                    float e = a_s[s] + ad;
                    e = (e > 0.f) ? e : NEG_SLOPE * e;
                    wgt = __expf(e);
                }
                dpart += wgt;
                // phase 2: stream rows, 4 in flight, group-internal shfl
                for (int k = 0; k < cnt; k += 4) {
                    int si[4];
                    float wt[4];
#pragma unroll
                    for (int u = 0; u < 4; ++u) {
                        int c = k + u;
                        int cc = (c < cnt) ? c : 0;
                        si[u] = __shfl(s, glane | cc);
                        wt[u] = __shfl(wgt, glane | cc);
                        if (c >= cnt) wt[u] = 0.f;
                    }
                    bf16x8 r[4];
#pragma unroll
                    for (int u = 0; u < 4; ++u)
                        r[u] = *(const bf16x8*)(xpb + (size_t)si[u] * HD + fg * 8);
#pragma unroll
                    for (int u = 0; u < 4; ++u)
#pragma unroll
                        for (int j = 0; j < 8; ++j) acc[j] += wt[u] * b2f(r[u][j]);
                }
            }
            // denom reduce across the 16-lane group
            dpart += __shfl_xor(dpart, 8);
            dpart += __shfl_xor(dpart, 4);
            dpart += __shfl_xor(dpart, 2);
            dpart += __shfl_xor(dpart, 1);
            float inv = __fdividef(1.f, dpart);
            bf16x8 sh, sl;
#pragma unroll
            for (int j = 0; j < 8; ++j) {
                float o = acc[j] * inv + bias_g[fg * 8 + j];
                o = fmaxf(o, 0.f);
                short hi = f2bf(o);
                sh[j] = hi;
                sl[j] = f2bf(o - b2f(hi));
            }
            sSH[sidx] = sh;
            sSL[sidx] = sl;
        } else {
            bf16x8 z;
#pragma unroll
            for (int j = 0; j < 8; ++j) z[j] = 0;
            sSH[sidx] = z;
            sSL[sidx] = z;
        }
    }

    // ---- convert + write h tiles (loads drained long ago) ----
#pragma unroll
    for (int q = 0; q < 2; ++q) {
        int ks = w * 2 + q;
        bf16x8 hh, hl;
#pragma unroll
        for (int j = 0; j < 8; ++j) {
            short b = f2bf(h8[q][j]);
            hh[j] = b;
            hl[j] = f2bf(h8[q][j] - b2f(b));
        }
        int li = ks * 64 + lane;
        sHH[li] = hh;
        sHL[li] = hl;
    }
    __syncthreads();

    // ---- GRU phase: 2-pass K-loop (R7) ----
    int j0 = w * 32;
    int cj = lane & 31;       // column within wave's 32-col slab
    int kh = lane >> 5;       // k-half for frags

    // fragment-ordered weight base for this wave: + g*65536 + ks*2048 + which*512
    const short* wb = wfrag + (size_t)w * 16384 + (size_t)lane * 8;

    // ---- pass A: r and z gates (merged ih+hh accumulators) ----
    f32x16 arz0, arz1;
#pragma unroll
    for (int r = 0; r < 16; ++r) { arz0[r] = 0.f; arz1[r] = 0.f; }

#pragma unroll
    for (int ks = 0; ks < 8; ++ks) {
        int li = ks * 64 + lane;
        bf16x8 aSH = sSH[li];
        bf16x8 aSL = sSL[li];
        bf16x8 aHH = sHH[li];
        bf16x8 aHL = sHL[li];
        {
            const short* p = wb + 0 * 65536 + ks * 2048;
            bf16x8 wih = *(const bf16x8*)(p);
            bf16x8 wil = *(const bf16x8*)(p + 512);
            bf16x8 whh = *(const bf16x8*)(p + 1024);
            bf16x8 whl = *(const bf16x8*)(p + 1536);
            arz0 = __builtin_amdgcn_mfma_f32_32x32x16_bf16(aSH, wih, arz0, 0, 0, 0);
            arz0 = __builtin_amdgcn_mfma_f32_32x32x16_bf16(aHH, whh, arz0, 0, 0, 0);
            arz0 = __builtin_amdgcn_mfma_f32_32x32x16_bf16(aSL, wih, arz0, 0, 0, 0);
            arz0 = __builtin_amdgcn_mfma_f32_32x32x16_bf16(aHL, whh, arz0, 0, 0, 0);
            arz0 = __builtin_amdgcn_mfma_f32_32x32x16_bf16(aSH, wil, arz0, 0, 0, 0);
            arz0 = __builtin_amdgcn_mfma_f32_32x32x16_bf16(aHH, whl, arz0, 0, 0, 0);
        }
        {
            const short* p = wb + 1 * 65536 + ks * 2048;
            bf16x8 wih = *(const bf16x8*)(p);
            bf16x8 wil = *(const bf16x8*)(p + 512);
            bf16x8 whh = *(const bf16x8*)(p + 1024);
            bf16x8 whl = *(const bf16x8*)(p + 1536);
            arz1 = __builtin_amdgcn_mfma_f32_32x32x16_bf16(aSH, wih, arz1, 0, 0, 0);
            arz1 = __builtin_amdgcn_mfma_f32_32x32x16_bf16(aHH, whh, arz1, 0, 0, 0);
            arz1 = __builtin_amdgcn_mfma_f32_32x32x16_bf16(aSL, wih, arz1, 0, 0, 0);
            arz1 = __builtin_amdgcn_mfma_f32_32x32x16_bf16(aHL, whh, arz1, 0, 0, 0);
            arz1 = __builtin_amdgcn_mfma_f32_32x32x16_bf16(aSH, wil, arz1, 0, 0, 0);
            arz1 = __builtin_amdgcn_mfma_f32_32x32x16_bf16(aHH, whl, arz1, 0, 0, 0);
        }
    }

    // ---- pass B: n gate (separate ih/hh accumulators; r gates h_n) ----
    f32x16 ain, ahn;
#pragma unroll
    for (int r = 0; r < 16; ++r) { ain[r] = 0.f; ahn[r] = 0.f; }

#pragma unroll
    for (int ks = 0; ks < 8; ++ks) {
        int li = ks * 64 + lane;
        bf16x8 aSH = sSH[li];
        bf16x8 aSL = sSL[li];
        bf16x8 aHH = sHH[li];
        bf16x8 aHL = sHL[li];
        const short* p = wb + 2 * 65536 + ks * 2048;
        bf16x8 wih = *(const bf16x8*)(p);
        bf16x8 wil = *(const bf16x8*)(p + 512);
        bf16x8 whh = *(const bf16x8*)(p + 1024);
        bf16x8 whl = *(const bf16x8*)(p + 1536);
        ain = __builtin_amdgcn_mfma_f32_32x32x16_bf16(aSH, wih, ain, 0, 0, 0);
        ahn = __builtin_amdgcn_mfma_f32_32x32x16_bf16(aHH, whh, ahn, 0, 0, 0);
        ain = __builtin_amdgcn_mfma_f32_32x32x16_bf16(aSL, wih, ain, 0, 0, 0);
        ahn = __builtin_amdgcn_mfma_f32_32x32x16_bf16(aHL, whh, ahn, 0, 0, 0);
        ain = __builtin_amdgcn_mfma_f32_32x32x16_bf16(aSH, wil, ain, 0, 0, 0);
        ahn = __builtin_amdgcn_mfma_f32_32x32x16_bf16(aHH, whl, ahn, 0, 0, 0);
    }

    // ---- wave-local GRU elementwise + h write ----
    int j = j0 + cj;
    float brz0 = b_ih[j] + b_hh[j];
    float brz1 = b_ih[HD + j] + b_hh[HD + j];
    float bin_ = b_ih[2 * HD + j];
    float bhn = b_hh[2 * HD + j];
    const short* hhs = (const short*)sHH;
    const short* hls = (const short*)sHL;
    int ksj = j >> 4, halfj = (j >> 3) & 1, ej = j & 7;

#pragma unroll
    for (int r = 0; r < 16; ++r) {
        int nl = (r & 3) + 8 * (r >> 2) + 4 * kh;  // C/D row mapping (m74/m101)
        int node = n0 + nl;
        if (node < n) {
            float rr = __fdividef(1.f, 1.f + __expf(-(arz0[r] + brz0)));
            float zz = __fdividef(1.f, 1.f + __expf(-(arz1[r] + brz1)));
            float u = ain[r] + bin_ + rr * (ahn[r] + bhn);
            float ex = __expf(2.f * u);
            float nn2 = 1.f - __fdividef(2.f, ex + 1.f);  // tanh(u)
            int li = (ksj * 64 + nl + 32 * halfj) * 8 + ej;
            float hold = b2f(hhs[li]) + b2f(hls[li]);
            h[(size_t)node * HD + j] = (1.f - zz) * nn2 + zz * hold;
        }
    }

    // ---- xp TAIL (R12: float4-vectorized Wg/att reads) ----
    // 8 threads per node, 16 consecutive columns each. Wg reads: 4x float4
    // per k-row (64 ops/wave x 8 lines) vs 256 scalar ops (x8 lines) before.
    if (x_next != nullptr) {
        int node = n0 + (t >> 3);
        int sub = t & 7;            // cols sub*16 .. sub*16+15
        if (node < n) {
            const float* xr = x_next + (size_t)node * FIN;
            float xv[FIN];
#pragma unroll
            for (int k = 0; k < FIN; ++k) xv[k] = xr[k];
            float vacc[16];
#pragma unroll
            for (int c = 0; c < 16; ++c) vacc[c] = 0.f;
#pragma unroll
            for (int k = 0; k < FIN; ++k) {
                const float4* wrow = (const float4*)(Wg + k * HD + sub * 16);
                float xk = xv[k];
#pragma unroll
                for (int q = 0; q < 4; ++q) {
                    float4 w4 = wrow[q];
                    vacc[q * 4 + 0] += xk * w4.x;
                    vacc[q * 4 + 1] += xk * w4.y;
                    vacc[q * 4 + 2] += xk * w4.z;
                    vacc[q * 4 + 3] += xk * w4.w;
                }
            }
            const float4* as4 = (const float4*)(att_src + sub * 16);
            const float4* ad4 = (const float4*)(att_dst + sub * 16);
            float s = 0.f, d = 0.f;
#pragma unroll
            for (int q = 0; q < 4; ++q) {
                float4 a4 = as4[q];
                float4 d4 = ad4[q];
                s += vacc[q * 4 + 0] * a4.x + vacc[q * 4 + 1] * a4.y +
                     vacc[q * 4 + 2] * a4.z + vacc[q * 4 + 3] * a4.w;
                d += vacc[q * 4 + 0] * d4.x + vacc[q * 4 + 1] * d4.y +
                     vacc[q * 4 + 2] * d4.z + vacc[q * 4 + 3] * d4.w;
            }
            unsigned pk[8];
#pragma unroll
            for (int c = 0; c < 16; c += 2)
                pk[c >> 1] = (unsigned)(unsigned short)f2bf(vacc[c]) |
                             ((unsigned)(unsigned short)f2bf(vacc[c + 1]) << 16);
            unsigned* dstw = xpb_next + (size_t)node * 64 + sub * 8;
            *(uint4*)(dstw) = make_uint4(pk[0], pk[1], pk[2], pk[3]);
            *(uint4*)(dstw + 4) = make_uint4(pk[4], pk[5], pk[6], pk[7]);
            // reduce a_s/a_d across the node's 8 threads (same wave)
            s += __shfl_xor(s, 1); s += __shfl_xor(s, 2); s += __shfl_xor(s, 4);
            d += __shfl_xor(d, 1); d += __shfl_xor(d, 2); d += __shfl_xor(d, 4);
            if (sub == 0) { a_s_next[node] = s; a_d_next[node] = d; }
        }
    }
}

// out[n] = h[n] . W_fc + b_fc   (one wave per node)
__global__ __launch_bounds__(256) void fc_kernel(
    const float* __restrict__ h, const float* __restrict__ W_fc,
    const float* __restrict__ b_fc, float* __restrict__ out, int n) {
    int wave = (blockIdx.x * blockDim.x + threadIdx.x) >> 6;
    int lane = threadIdx.x & 63;
    if (wave >= n) return;
    float v = h[(size_t)wave * HD + lane] * W_fc[lane] +
              h[(size_t)wave * HD + lane + 64] * W_fc[lane + 64];
#pragma unroll
    for (int off = 32; off; off >>= 1) v += __shfl_xor(v, off);
    if (lane == 0) out[wave] = v + b_fc[0];
}

// ---------------------------------------------------------------------------
extern "C" void kernel_launch(void* const* d_in, const int* in_sizes, int n_in,
                              void* d_out, int out_size, void* d_ws, size_t ws_size,
                              hipStream_t stream) {
    const float* x_seq   = (const float*)d_in[0];
    const int*   ei      = (const int*)d_in[1];
    const float* Wg      = (const float*)d_in[2];
    const float* att_src = (const float*)d_in[3];
    const float* att_dst = (const float*)d_in[4];
    const float* bias_g  = (const float*)d_in[5];
    const float* W_ih    = (const float*)d_in[6];
    const float* W_hh    = (const float*)d_in[7];
    const float* b_ih    = (const float*)d_in[8];
    const float* b_hh    = (const float*)d_in[9];
    const float* W_fc    = (const float*)d_in[10];
    const float* b_fc    = (const float*)d_in[11];
    float* out = (float*)d_out;

    const int N = NN;
    const int E = in_sizes[1] / 2;
    const int* src = ei;
    const int* dst = ei + E;

    // workspace layout
    char* w = (char*)d_ws;
    size_t off = 0;
    auto alloc = [&](size_t bytes) {
        char* p = w + off;
        off = (off + bytes + 255) & ~(size_t)255;
        return p;
    };
    int*   deg     = (int*)alloc((size_t)N * 4);
    int*   row_ptr = (int*)alloc((size_t)(N + 1) * 4);
    int*   cursor  = (int*)alloc((size_t)N * 4);
    int*   col     = (int*)alloc((size_t)(E + N) * 4);
    float* a_s0    = (float*)alloc((size_t)N * 4);
    float* a_d0    = (float*)alloc((size_t)N * 4);
    float* a_s1    = (float*)alloc((size_t)N * 4);
    float* a_d1    = (float*)alloc((size_t)N * 4);
    unsigned* xpb0 = (unsigned*)alloc((size_t)N * 64 * 4);   // bf16 xp [N][128]
    unsigned* xpb1 = (unsigned*)alloc((size_t)N * 64 * 4);
    float* hbuf    = (float*)alloc((size_t)N * HD * 4);
    short* wfrag   = (short*)alloc((size_t)3 * 4 * 8 * 4 * 64 * 8 * 2);  // 393KB

    unsigned* xpbs[2] = {xpb0, xpb1};
    float* a_ss[2] = {a_s0, a_s1};
    float* a_ds[2] = {a_d0, a_d1};

    // h0 = 0
    hipMemsetAsync(hbuf, 0, (size_t)N * HD * 4, stream);

    // CSR build + weight pack (once per launch)
    deg_init_kernel<<<(N + 255) / 256, 256, 0, stream>>>(deg, N);
    deg_count_kernel<<<(E + 255) / 256, 256, 0, stream>>>(dst, deg, E);
    scan_kernel<<<1, 1024, 0, stream>>>(deg, row_ptr, N);
    selfloop_kernel<<<(N + 255) / 256, 256, 0, stream>>>(row_ptr, cursor, col, N);
    scatter_kernel<<<(E + 255) / 256, 256, 0, stream>>>(src, dst, cursor, col, E);
    wpack_kernel<<<(24576 + 255) / 256, 256, 0, stream>>>(W_ih, W_hh, wfrag);

    int node_wave_blocks = (N * 64 + 255) / 256;  // one wave per node
    int fused_blocks = (N + 31) / 32;             // 32-node fused tiles

    // prologue: xp for t=0 into buffer 0
    xp_kernel<<<node_wave_blocks, 256, 0, stream>>>(x_seq, Wg, att_src, att_dst,
                                                    xpb0, a_s0, a_d0, N);

    for (int t = 0; t < SEQ; ++t) {
        int cur = t & 1, nxt = cur ^ 1;
        const float* xnext = (t + 1 < SEQ) ? (x_seq + (size_t)(t + 1) * N * FIN)
                                           : nullptr;
        gatgru_kernel<<<fused_blocks, 256, 0, stream>>>(
            row_ptr, col, a_ss[cur], a_ds[cur], (const short*)xpbs[cur], bias_g,
            hbuf, wfrag, b_ih, b_hh, N,
            xnext, Wg, att_src, att_dst, xpbs[nxt], a_ss[nxt], a_ds[nxt]);
    }
    fc_kernel<<<node_wave_blocks, 256, 0, stream>>>(hbuf, W_fc, b_fc, out, N);
}